// Round 4
// baseline (296.283 us; speedup 1.0000x reference)
//
#include <hip/hip_runtime.h>
#include <hip/hip_bf16.h>

typedef __bf16 bf16;
typedef __bf16 bf16x4 __attribute__((ext_vector_type(4)));
typedef __bf16 bf16x8 __attribute__((ext_vector_type(8)));
typedef float  f32x4  __attribute__((ext_vector_type(4)));

#define T_SZ   4096
#define NFREQ  512
#define HOP    512
#define OUT_LEN 2097664   // 4097 * 512
#define NTT33  33
#define XROWS  4097       // phys rows per batch in Xw: row r holds t = r-1 (row 0 = zeros)

#define XW_ELEMS ((size_t)16 * XROWS * 1024)
#define WT_ELEMS ((size_t)1024 * 1024)
#define WS_NEED  ((XW_ELEMS + WT_ELEMS) * 2)

#define LDS_BYTES 82048   // 2 x (A 512x32 + B 129x32) bf16

__device__ __forceinline__ void gl16(const void* g, void* l) {
    __builtin_amdgcn_global_load_lds(
        (const __attribute__((address_space(1))) void*)g,
        (__attribute__((address_space(3))) void*)l, 16, 0, 0);
}

// ---------- Wt[j][k] = k<512 ? rk[j][k] : ik[j][k-512] ----------
__global__ __launch_bounds__(256, 4) void cvt_w(const float* __restrict__ rk,
                                                const float* __restrict__ ik,
                                                bf16* __restrict__ Wt) {
    const int j  = blockIdx.x;
    const int k4 = threadIdx.x * 4;
    const float* s = (k4 < NFREQ) ? &rk[j * NFREQ + k4] : &ik[j * NFREQ + k4 - NFREQ];
    f32x4 v = *(const f32x4*)s;
    bf16x4 h;
    h[0] = (bf16)v[0]; h[1] = (bf16)v[1]; h[2] = (bf16)v[2]; h[3] = (bf16)v[3];
    *(bf16x4*)&Wt[((size_t)j << 10) + k4] = h;
}

// ---------- zero phys row 0 of each batch (t = -1) ----------
__global__ void zpad(bf16* __restrict__ Xw) {
    const int b = blockIdx.x, tid = threadIdx.x;   // 16 x 128
    bf16x8 z = {};
    *(bf16x8*)&Xw[(((size_t)b * XROWS) << 10) + tid * 8] = z;
}

// ---------- Xw[b][1+t][k] = (k<512?magn:phase)[b][k%512][t] ----------
__global__ __launch_bounds__(256, 4) void cvt_x(const float* __restrict__ magn,
                                                const float* __restrict__ phase,
                                                bf16* __restrict__ Xw) {
    __shared__ bf16 t2[64][132];
    const int tid = threadIdx.x;
    const int bid = blockIdx.x;
    const int kt  = bid & 15;
    const int tt  = (bid >> 4) & 31;
    const int b   = bid >> 9;
    const float* src = (kt < 8 ? magn : phase)
                     + ((size_t)b * NFREQ + (kt & 7) * 64) * T_SZ + tt * 128;
    const int fr = tid >> 5;
    const int c  = (tid & 31) * 4;
    #pragma unroll
    for (int p = 0; p < 8; ++p) {
        const int f = fr + 8 * p;
        f32x4 v = *(const f32x4*)&src[(size_t)f * T_SZ + c];
        bf16x4 h;
        h[0] = (bf16)v[0]; h[1] = (bf16)v[1]; h[2] = (bf16)v[2]; h[3] = (bf16)v[3];
        *(bf16x4*)&t2[f][c] = h;
    }
    __syncthreads();
    const int koff = (tid & 7) * 8;
    bf16* dstb = Xw + (((size_t)b * XROWS + 1 + tt * 128) << 10) + kt * 64 + koff;
    #pragma unroll
    for (int q = 0; q < 4; ++q) {
        const int tr = (tid >> 3) + 32 * q;
        bf16x8 o;
        #pragma unroll
        for (int ki = 0; ki < 8; ++ki) o[ki] = t2[koff + ki][tr];
        *(bf16x8*)&dstb[(size_t)tr << 10] = o;
    }
}

// ---------- main GEMM: 256j x 128t tile, BK=32, counted-vmcnt pipeline ----------
// A-tile rows 0..255 = Wt[j0+r] (lo), 256..511 = Wt[j0+512+(r-256)] (hi).
// B-tile row r (0..128) = X[t0-1+r] (phys Xw row t0+r, always valid).
// swizzle: 16B slot' = slot ^ ((row ^ row>>2)&3), applied on gl16 SOURCE and ds_read.
__global__ __launch_bounds__(512, 2) void istft_gemm2(
    const bf16* __restrict__ Xw, const bf16* __restrict__ Wt,
    const float* __restrict__ acv, float* __restrict__ out)
{
    extern __shared__ __attribute__((aligned(16))) bf16 lds[];
    bf16* A0 = lds;                 // 16384
    bf16* B0 = lds + 16384;         // 4128
    bf16* A1 = lds + 20512;
    bf16* B1 = lds + 20512 + 16384;

    const int tid = threadIdx.x;
    const int w   = tid >> 6;       // 8 waves: wr = w>>1 (4 j-blocks), wc = w&1 (2 t-halves)
    const int l   = tid & 63;

    const int bid = blockIdx.x;     // 1024 = 512 panels x 2 j-tiles; panel -> xcd = bid&7
    const int xcd = bid & 7;
    const int jt  = (bid >> 3) & 1;
    const int pg  = bid >> 4;
    const int pnl = pg * 8 + xcd;   // 0..511
    const int b   = pnl >> 5;
    const int tt0 = pnl & 31;
    const int j0  = jt * 256;
    const int t0  = tt0 * 128;

    // staging maps: 64B rows, 4 slots; lane -> row base+(l>>2), slot l&3
    const int arow = 16 * w + (l >> 2);
    const int ssrc = ((l & 3) ^ ((l >> 2) & 3) ^ ((l >> 4) & 3)) * 8;  // pre-swizzled src slot
    size_t agj[4];
    #pragma unroll
    for (int i = 0; i < 4; ++i) {
        const int r  = 128 * i + arow;
        const int gj = (r < 256) ? (j0 + r) : (j0 + 256 + r);
        agj[i] = ((size_t)gj << 10);
    }
    const size_t xb    = (size_t)b * XROWS;
    const size_t bsrc  = (xb + t0 + arow) << 10;
    const size_t bsrcX = (xb + t0 + 128) << 10;

    auto stage = [&](bf16* Ab, bf16* Bb, int ks) {
        const int k0 = ks * 32;
        #pragma unroll
        for (int i = 0; i < 4; ++i)
            gl16(Wt + agj[i] + k0 + ssrc, Ab + (128 * i + 16 * w) * 32);
        gl16(Xw + bsrc + k0 + ssrc, Bb + (16 * w) * 32);
        if (l < 4)
            gl16(Xw + bsrcX + k0 + l * 8, Bb + 128 * 32);
    };

    f32x4 acc[4][4];
    #pragma unroll
    for (int i = 0; i < 4; ++i)
        #pragma unroll
        for (int j = 0; j < 4; ++j)
            acc[i][j] = (f32x4){0.f, 0.f, 0.f, 0.f};

    const int wr = w >> 1, wc = w & 1;
    const int c15 = l & 15, c4 = l >> 4;

    stage(A0, B0, 0);
    stage(A1, B1, 1);

    int p = 0;
    for (int ks = 0; ks < 32; ++ks) {
        bf16* Ab = p ? A1 : A0;
        bf16* Bb = p ? B1 : B0;

        if (ks < 31) asm volatile("s_waitcnt vmcnt(6)" ::: "memory");
        else         asm volatile("s_waitcnt vmcnt(0)" ::: "memory");
        __builtin_amdgcn_s_barrier();

        bf16x8 Alo[4], Ahi[4], Blo[4], Bhi[4];
        #pragma unroll
        for (int m = 0; m < 4; ++m) {
            const int r = wr * 64 + m * 16 + c15;            // 0..255
            const int s = ((c4 ^ r ^ (r >> 2)) & 3) * 8;     // same for r and r+256
            Alo[m] = *(const bf16x8*)&Ab[r * 32 + s];
            Ahi[m] = *(const bf16x8*)&Ab[(r + 256) * 32 + s];
        }
        #pragma unroll
        for (int n = 0; n < 4; ++n) {
            const int rH = wc * 64 + n * 16 + c15;           // 0..127 (t = tt-1)
            const int sH = ((c4 ^ rH ^ (rH >> 2)) & 3) * 8;
            Bhi[n] = *(const bf16x8*)&Bb[rH * 32 + sH];
            const int rL = rH + 1;                           // t = tt
            const int sL = ((c4 ^ rL ^ (rL >> 2)) & 3) * 8;
            Blo[n] = *(const bf16x8*)&Bb[rL * 32 + sL];
        }
        asm volatile("s_waitcnt lgkmcnt(0)" ::: "memory");   // reads done -> LDS reusable
        __builtin_amdgcn_sched_barrier(0);
        __builtin_amdgcn_s_barrier();                        // all waves done reading buf p

        if (ks + 2 < 32) stage(Ab, Bb, ks + 2);              // prefetch into freed buffer

        __builtin_amdgcn_s_setprio(1);
        #pragma unroll
        for (int m = 0; m < 4; ++m)
            #pragma unroll
            for (int n = 0; n < 4; ++n) {
                acc[m][n] = __builtin_amdgcn_mfma_f32_16x16x32_bf16(
                    Alo[m], Blo[n], acc[m][n], 0, 0, 0);
                acc[m][n] = __builtin_amdgcn_mfma_f32_16x16x32_bf16(
                    Ahi[m], Bhi[n], acc[m][n], 0, 0, 0);
            }
        __builtin_amdgcn_s_setprio(0);
        p ^= 1;
    }

    // epilogue: out[tt*512+jl] = (lo + hi + ac[tt] + ac[tt-1]) / 1024
    const float inv = 1.0f / 1024.0f;
    float* ob = out + (size_t)b * OUT_LEN;
    const float* acb = acv + (size_t)b * T_SZ;
    const int jbase = j0 + wr * 64 + c4 * 4;
    #pragma unroll
    for (int n = 0; n < 4; ++n) {
        const int tt = t0 + wc * 64 + n * 16 + c15;          // <= 4095 always
        const float acs = acb[tt] + (tt ? acb[tt - 1] : 0.f);
        #pragma unroll
        for (int m = 0; m < 4; ++m) {
            f32x4 v;
            #pragma unroll
            for (int rr = 0; rr < 4; ++rr)
                v[rr] = (acc[m][n][rr] + acs) * inv;
            __builtin_nontemporal_store(v, (f32x4*)&ob[(size_t)tt * HOP + jbase + m * 16]);
        }
    }
}

// ---------- tail: out column t=4096 (hi term only) ----------
__global__ __launch_bounds__(256, 2) void istft_tail(
    const bf16* __restrict__ Xw, const bf16* __restrict__ Wt,
    const float* __restrict__ acv, float* __restrict__ out)
{
    __shared__ float xf[1024];
    const int b = blockIdx.x, tid = threadIdx.x;
    const bf16* xr = Xw + (((size_t)b * XROWS + 4096) << 10);   // t = 4095
    {
        bf16x4 v = *(const bf16x4*)&xr[tid * 4];
        xf[tid * 4 + 0] = (float)v[0]; xf[tid * 4 + 1] = (float)v[1];
        xf[tid * 4 + 2] = (float)v[2]; xf[tid * 4 + 3] = (float)v[3];
    }
    __syncthreads();
    const float acs = acv[b * T_SZ + 4095];
    float s0 = 0.f, s1 = 0.f;
    const bf16* w0 = Wt + ((size_t)(512 + tid) << 10);
    const bf16* w1 = w0 + ((size_t)256 << 10);
    for (int kc = 0; kc < 128; ++kc) {
        bf16x8 a = *(const bf16x8*)&w0[kc * 8];
        bf16x8 c = *(const bf16x8*)&w1[kc * 8];
        #pragma unroll
        for (int e = 0; e < 8; ++e) {
            const float xv = xf[kc * 8 + e];
            s0 += xv * (float)a[e];
            s1 += xv * (float)c[e];
        }
    }
    float* ob = out + (size_t)b * OUT_LEN + (size_t)4096 * HOP;
    ob[tid]       = (s0 + acs) * (1.f / 1024.f);
    ob[tid + 256] = (s1 + acs) * (1.f / 1024.f);
}

// ---------- fallback (round-2 kernel, no workspace needed) ----------
#define LDBL 40
__global__ __launch_bounds__(256, 2) void istft_fused_legacy(
    const float* __restrict__ magn, const float* __restrict__ phase,
    const float* __restrict__ acv,
    const float* __restrict__ rk,  const float* __restrict__ ik,
    float* __restrict__ out)
{
    __shared__ __attribute__((aligned(16))) bf16 As[2][128 * LDBL];
    __shared__ __attribute__((aligned(16))) bf16 Bs[2][129 * LDBL];
    const int tid = threadIdx.x;
    const int w = tid >> 6, l = tid & 63;
    const int bid = blockIdx.x;
    const int xcd = bid & 7, q = bid >> 3;
    const int jt = q & 7, pgrp = q >> 3;
    const int pnl = pgrp * 8 + xcd;
    const int b = pnl / NTT33, tt0 = pnl - b * NTT33;
    const int j0 = jt * 64, t0 = tt0 * 128;
    const float* xm = magn  + (size_t)b * NFREQ * T_SZ;
    const float* xp = phase + (size_t)b * NFREQ * T_SZ;
    const int jrow = tid >> 3, fc = (tid & 7) * 4;
    const int f0 = (tid >> 5) * 4, tl = tid & 31;
    f32x4 areg[4]; float vreg[4][4]; float rz = 0.f;
    f32x4 acc[8][2];
    #pragma unroll
    for (int i = 0; i < 8; ++i)
        #pragma unroll
        for (int j = 0; j < 2; ++j) acc[i][j] = (f32x4){0.f, 0.f, 0.f, 0.f};
    const int nbase = w * 32;
    auto loadA = [&](int ks) {
        const int k0 = ks * 32;
        const float* wsrc = (k0 < NFREQ) ? (rk + k0) : (ik + (k0 - NFREQ));
        #pragma unroll
        for (int i = 0; i < 4; ++i) {
            const int jr = jrow + 32 * i;
            const int j = (jr < 64) ? (j0 + jr) : (j0 + 448 + jr);
            areg[i] = *(const f32x4*)&wsrc[(size_t)j * NFREQ + fc];
        }
    };
    auto writeA = [&](int p) {
        #pragma unroll
        for (int i = 0; i < 4; ++i) {
            bf16x4 v;
            v[0] = (bf16)areg[i][0]; v[1] = (bf16)areg[i][1];
            v[2] = (bf16)areg[i][2]; v[3] = (bf16)areg[i][3];
            *(bf16x4*)&As[p][(jrow + 32 * i) * LDBL + fc] = v;
        }
    };
    auto loadB = [&](int ks) {
        const int k0 = ks * 32;
        const float* xbp = (k0 < NFREQ) ? (xm + (size_t)k0 * T_SZ)
                                        : (xp + (size_t)(k0 - NFREQ) * T_SZ);
        #pragma unroll
        for (int i = 0; i < 4; ++i) {
            if (t0 + 32 * i + 32 <= T_SZ) {
                #pragma unroll
                for (int fj = 0; fj < 4; ++fj)
                    vreg[fj][i] = xbp[(size_t)(f0 + fj) * T_SZ + t0 + tl + 32 * i];
            } else {
                #pragma unroll
                for (int fj = 0; fj < 4; ++fj) vreg[fj][i] = 0.f;
            }
        }
        if (tid < 32) rz = (t0 >= 1) ? xbp[(size_t)tid * T_SZ + (t0 - 1)] : 0.f;
    };
    auto writeB = [&](int p) {
        #pragma unroll
        for (int i = 0; i < 4; ++i) {
            bf16x4 v;
            v[0] = (bf16)vreg[0][i]; v[1] = (bf16)vreg[1][i];
            v[2] = (bf16)vreg[2][i]; v[3] = (bf16)vreg[3][i];
            *(bf16x4*)&Bs[p][(1 + tl + 32 * i) * LDBL + f0] = v;
        }
        if (tid < 32) Bs[p][tid] = (bf16)rz;
    };
    loadA(0); loadB(0); writeA(0); writeB(0);
    __syncthreads();
    int p = 0;
    for (int ks = 0; ks < 32; ++ks) {
        if (ks + 1 < 32) { loadA(ks + 1); loadB(ks + 1); }
        bf16x8 af[8], blv[2], bhv[2];
        #pragma unroll
        for (int mi = 0; mi < 8; ++mi)
            af[mi] = *(const bf16x8*)&As[p][(mi * 16 + (l & 15)) * LDBL + (l >> 4) * 8];
        #pragma unroll
        for (int ni = 0; ni < 2; ++ni) {
            const int rb = nbase + ni * 16 + (l & 15);
            bhv[ni] = *(const bf16x8*)&Bs[p][rb * LDBL + (l >> 4) * 8];
            blv[ni] = *(const bf16x8*)&Bs[p][(rb + 1) * LDBL + (l >> 4) * 8];
        }
        #pragma unroll
        for (int ni = 0; ni < 2; ++ni)
            #pragma unroll
            for (int mi = 0; mi < 4; ++mi) {
                acc[mi][ni] = __builtin_amdgcn_mfma_f32_16x16x32_bf16(af[mi], blv[ni], acc[mi][ni], 0, 0, 0);
                acc[mi + 4][ni] = __builtin_amdgcn_mfma_f32_16x16x32_bf16(af[mi + 4], bhv[ni], acc[mi + 4][ni], 0, 0, 0);
            }
        if (ks + 1 < 32) { writeA(p ^ 1); writeB(p ^ 1); }
        __syncthreads();
        p ^= 1;
    }
    const float inv = 1.0f / 1024.0f;
    float* ob = out + (size_t)b * OUT_LEN;
    const float* acb = acv + (size_t)b * T_SZ;
    #pragma unroll
    for (int ni = 0; ni < 2; ++ni) {
        const int tt = t0 + nbase + ni * 16 + (l & 15);
        if (tt <= T_SZ) {
            float acs = 0.f;
            if (tt < T_SZ) acs += acb[tt];
            if (tt >= 1)   acs += acb[tt - 1];
            #pragma unroll
            for (int mi = 0; mi < 4; ++mi) {
                const int jl = j0 + mi * 16 + (l >> 4) * 4;
                f32x4 v;
                #pragma unroll
                for (int rr = 0; rr < 4; ++rr)
                    v[rr] = (acc[mi][ni][rr] + acc[mi + 4][ni][rr] + acs) * inv;
                __builtin_nontemporal_store(v, (f32x4*)&ob[(size_t)tt * HOP + jl]);
            }
        }
    }
}

extern "C" void kernel_launch(void* const* d_in, const int* in_sizes, int n_in,
                              void* d_out, int out_size, void* d_ws, size_t ws_size,
                              hipStream_t stream) {
    const float* magn  = (const float*)d_in[0];
    const float* phase = (const float*)d_in[1];
    const float* ac    = (const float*)d_in[2];
    const float* rk    = (const float*)d_in[3];
    const float* ik    = (const float*)d_in[4];
    float* out = (float*)d_out;

    bool ok = (ws_size >= WS_NEED);
    if (ok) {
        if (hipFuncSetAttribute((const void*)istft_gemm2,
                hipFuncAttributeMaxDynamicSharedMemorySize, LDS_BYTES) != hipSuccess)
            ok = false;
    }
    if (ok) {
        bf16* Xw = (bf16*)d_ws;
        bf16* Wt = Xw + XW_ELEMS;
        cvt_w<<<1024, 256, 0, stream>>>(rk, ik, Wt);
        zpad<<<16, 128, 0, stream>>>(Xw);
        cvt_x<<<8192, 256, 0, stream>>>(magn, phase, Xw);
        istft_gemm2<<<1024, 512, LDS_BYTES, stream>>>(Xw, Wt, ac, out);
        istft_tail<<<16, 256, 0, stream>>>(Xw, Wt, ac, out);
    } else {
        istft_fused_legacy<<<528 * 8, 256, 0, stream>>>(magn, phase, ac, rk, ik, out);
    }
}

// Round 5
// 253.026 us; speedup vs baseline: 1.1710x; 1.1710x over previous
//
#include <hip/hip_runtime.h>
#include <hip/hip_bf16.h>

typedef __bf16 bf16;
typedef __bf16 bf16x4 __attribute__((ext_vector_type(4)));
typedef __bf16 bf16x8 __attribute__((ext_vector_type(8)));
typedef float  f32x4  __attribute__((ext_vector_type(4)));

#define T_SZ   4096
#define NFREQ  512
#define HOP    512
#define OUT_LEN 2097664   // 4097 * 512
#define NTT33  33
#define XROWS  4097       // phys rows per batch in Xw: row r holds t = r-1 (row 0 = zeros)

#define XW_ELEMS ((size_t)16 * XROWS * 1024)
#define WT_ELEMS ((size_t)1024 * 1024)
#define WS_NEED  ((XW_ELEMS + WT_ELEMS) * 2)

__device__ __forceinline__ void gl16(const void* g, void* l) {
    __builtin_amdgcn_global_load_lds(
        (const __attribute__((address_space(1))) void*)g,
        (__attribute__((address_space(3))) void*)l, 16, 0, 0);
}

// ---------- Wt[j][k] = k<512 ? rk[j][k] : ik[j][k-512] ----------
__global__ __launch_bounds__(256, 4) void cvt_w(const float* __restrict__ rk,
                                                const float* __restrict__ ik,
                                                bf16* __restrict__ Wt) {
    const int j  = blockIdx.x;
    const int k4 = threadIdx.x * 4;
    const float* s = (k4 < NFREQ) ? &rk[j * NFREQ + k4] : &ik[j * NFREQ + k4 - NFREQ];
    f32x4 v = *(const f32x4*)s;
    bf16x4 h;
    h[0] = (bf16)v[0]; h[1] = (bf16)v[1]; h[2] = (bf16)v[2]; h[3] = (bf16)v[3];
    *(bf16x4*)&Wt[((size_t)j << 10) + k4] = h;
}

// ---------- zero phys row 0 of each batch (t = -1) ----------
__global__ void zpad(bf16* __restrict__ Xw) {
    const int b = blockIdx.x, tid = threadIdx.x;   // 16 x 128
    bf16x8 z = {};
    *(bf16x8*)&Xw[(((size_t)b * XROWS) << 10) + tid * 8] = z;
}

// ---------- Xw[b][1+t][k] = (k<512?magn:phase)[b][k%512][t] ----------
__global__ __launch_bounds__(256, 4) void cvt_x(const float* __restrict__ magn,
                                                const float* __restrict__ phase,
                                                bf16* __restrict__ Xw) {
    __shared__ bf16 t2[64][132];
    const int tid = threadIdx.x;
    const int bid = blockIdx.x;
    const int kt  = bid & 15;
    const int tt  = (bid >> 4) & 31;
    const int b   = bid >> 9;
    const float* src = (kt < 8 ? magn : phase)
                     + ((size_t)b * NFREQ + (kt & 7) * 64) * T_SZ + tt * 128;
    const int fr = tid >> 5;
    const int c  = (tid & 31) * 4;
    #pragma unroll
    for (int p = 0; p < 8; ++p) {
        const int f = fr + 8 * p;
        f32x4 v = *(const f32x4*)&src[(size_t)f * T_SZ + c];
        bf16x4 h;
        h[0] = (bf16)v[0]; h[1] = (bf16)v[1]; h[2] = (bf16)v[2]; h[3] = (bf16)v[3];
        *(bf16x4*)&t2[f][c] = h;
    }
    __syncthreads();
    const int koff = (tid & 7) * 8;
    bf16* dstb = Xw + (((size_t)b * XROWS + 1 + tt * 128) << 10) + kt * 64 + koff;
    #pragma unroll
    for (int q = 0; q < 4; ++q) {
        const int tr = (tid >> 3) + 32 * q;
        bf16x8 o;
        #pragma unroll
        for (int ki = 0; ki < 8; ++ki) o[ki] = t2[koff + ki][tr];
        *(bf16x8*)&dstb[(size_t)tr << 10] = o;
    }
}

// ---------- main GEMM: fused 128j x 128t output tile, 4 waves, 3 blocks/CU ----------
// A-tile rows 0..127 = Wt[j0+r] (lo), 128..255 = Wt[j0+512+(r-128)] (hi).
// B-tile row r (0..128) = X[t0-1+r] = phys Xw row t0+r (always valid; row 0 of batch = 0).
// Swizzle (both sides, rule 21): 16B slot' = slot ^ ((row ^ row>>2)&3); gl16 keeps LDS
// linear and pre-swizzles the SOURCE slot; ds_read applies the same XOR.
__global__ __launch_bounds__(256, 3) void istft_gemm3(
    const bf16* __restrict__ Xw, const bf16* __restrict__ Wt,
    const float* __restrict__ acv, float* __restrict__ out)
{
    __shared__ __attribute__((aligned(16))) bf16 As[2][256 * 32];
    __shared__ __attribute__((aligned(16))) bf16 Bs[2][129 * 32];

    const int tid = threadIdx.x;
    const int w   = tid >> 6;      // 4 waves: wr = w>>1 (j half), wc = w&1 (t half)
    const int l   = tid & 63;

    const int bid = blockIdx.x;    // 2048 = 512 panels x 4 j-tiles; panel -> xcd = bid&7
    const int xcd = bid & 7;
    const int jt  = (bid >> 3) & 3;
    const int pg  = bid >> 5;      // 0..63
    const int pnl = pg * 8 + xcd;  // 0..511
    const int b   = pnl >> 5;
    const int tt0 = pnl & 31;
    const int j0  = jt * 128;
    const int t0  = tt0 * 128;

    // staging map: 64B rows of 4 slots; lane -> row chunk+(l>>2), slot l&3
    const int crow = l >> 2;                                           // 0..15
    const int ssrc = ((l & 3) ^ ((l >> 2) & 3) ^ ((l >> 4) & 3)) * 8;  // pre-swizzled src slot
    const int arow = 16 * w + crow;                                    // 0..63 per pass
    const size_t xb = (size_t)b * XROWS;

    size_t agj[4];
    #pragma unroll
    for (int i = 0; i < 4; ++i) {
        const int r  = 64 * i + arow;                       // A-tile row 0..255
        const int gj = (r < 128) ? (j0 + r) : (j0 + 384 + r);
        agj[i] = ((size_t)gj << 10);
    }
    const size_t bsrc0 = (xb + t0 + arow) << 10;            // B rows 0..63
    const size_t bsrc1 = (xb + t0 + 64 + arow) << 10;       // B rows 64..127
    const size_t bsrcX = (xb + t0 + 128) << 10;             // B row 128 (g(128)=0: linear)

    auto stage = [&](int p, int ks) {
        const int k0 = ks * 32;
        #pragma unroll
        for (int i = 0; i < 4; ++i)
            gl16(Wt + agj[i] + k0 + ssrc, &As[p][(64 * i + 16 * w) * 32]);
        gl16(Xw + bsrc0 + k0 + ssrc, &Bs[p][(16 * w) * 32]);
        gl16(Xw + bsrc1 + k0 + ssrc, &Bs[p][(64 + 16 * w) * 32]);
        if (w == 0 && l < 4)
            gl16(Xw + bsrcX + k0 + l * 8, &Bs[p][128 * 32]);
    };

    f32x4 acc[4][4];
    #pragma unroll
    for (int i = 0; i < 4; ++i)
        #pragma unroll
        for (int j = 0; j < 4; ++j)
            acc[i][j] = (f32x4){0.f, 0.f, 0.f, 0.f};

    const int wr = w >> 1, wc = w & 1;
    const int c15 = l & 15, c4 = l >> 4;

    stage(0, 0);
    __syncthreads();

    int p = 0;
    for (int ks = 0; ks < 32; ++ks) {
        if (ks + 1 < 32) stage(p ^ 1, ks + 1);   // issue next-tile loads first

        bf16x8 Alo[4], Ahi[4], Blo[4], Bhi[4];
        #pragma unroll
        for (int m = 0; m < 4; ++m) {
            const int r = wr * 64 + m * 16 + c15;            // 0..127
            const int s = ((c4 ^ r ^ (r >> 2)) & 3) * 8;     // same for r and r+128
            Alo[m] = *(const bf16x8*)&As[p][r * 32 + s];
            Ahi[m] = *(const bf16x8*)&As[p][(r + 128) * 32 + s];
        }
        #pragma unroll
        for (int n = 0; n < 4; ++n) {
            const int rH = wc * 64 + n * 16 + c15;           // 0..127 (t = tt-1)
            const int sH = ((c4 ^ rH ^ (rH >> 2)) & 3) * 8;
            Bhi[n] = *(const bf16x8*)&Bs[p][rH * 32 + sH];
            const int rL = rH + 1;                           // 1..128 (t = tt)
            const int sL = ((c4 ^ rL ^ (rL >> 2)) & 3) * 8;
            Blo[n] = *(const bf16x8*)&Bs[p][rL * 32 + sL];
        }
        #pragma unroll
        for (int m = 0; m < 4; ++m)
            #pragma unroll
            for (int n = 0; n < 4; ++n) {
                acc[m][n] = __builtin_amdgcn_mfma_f32_16x16x32_bf16(
                    Alo[m], Blo[n], acc[m][n], 0, 0, 0);
                acc[m][n] = __builtin_amdgcn_mfma_f32_16x16x32_bf16(
                    Ahi[m], Bhi[n], acc[m][n], 0, 0, 0);
            }

        __syncthreads();   // drains staging loads; hidden by 3 blocks/CU
        p ^= 1;
    }

    // epilogue: out[tt*512+jl] = (lo + hi + ac[tt] + ac[tt-1]) / 1024
    const float inv = 1.0f / 1024.0f;
    float* ob = out + (size_t)b * OUT_LEN;
    const float* acb = acv + (size_t)b * T_SZ;
    const int jbase = j0 + wr * 64 + c4 * 4;
    #pragma unroll
    for (int n = 0; n < 4; ++n) {
        const int tt = t0 + wc * 64 + n * 16 + c15;          // <= 4095 always
        const float acs = acb[tt] + (tt ? acb[tt - 1] : 0.f);
        #pragma unroll
        for (int m = 0; m < 4; ++m) {
            f32x4 v;
            #pragma unroll
            for (int rr = 0; rr < 4; ++rr)
                v[rr] = (acc[m][n][rr] + acs) * inv;
            __builtin_nontemporal_store(v, (f32x4*)&ob[(size_t)tt * HOP + jbase + m * 16]);
        }
    }
}

// ---------- tail: out column t=4096 (hi term only) ----------
__global__ __launch_bounds__(256, 2) void istft_tail(
    const bf16* __restrict__ Xw, const bf16* __restrict__ Wt,
    const float* __restrict__ acv, float* __restrict__ out)
{
    __shared__ float xf[1024];
    const int b = blockIdx.x, tid = threadIdx.x;
    const bf16* xr = Xw + (((size_t)b * XROWS + 4096) << 10);   // t = 4095
    {
        bf16x4 v = *(const bf16x4*)&xr[tid * 4];
        xf[tid * 4 + 0] = (float)v[0]; xf[tid * 4 + 1] = (float)v[1];
        xf[tid * 4 + 2] = (float)v[2]; xf[tid * 4 + 3] = (float)v[3];
    }
    __syncthreads();
    const float acs = acv[b * T_SZ + 4095];
    float s0 = 0.f, s1 = 0.f;
    const bf16* w0 = Wt + ((size_t)(512 + tid) << 10);
    const bf16* w1 = w0 + ((size_t)256 << 10);
    for (int kc = 0; kc < 128; ++kc) {
        bf16x8 a = *(const bf16x8*)&w0[kc * 8];
        bf16x8 c = *(const bf16x8*)&w1[kc * 8];
        #pragma unroll
        for (int e = 0; e < 8; ++e) {
            const float xv = xf[kc * 8 + e];
            s0 += xv * (float)a[e];
            s1 += xv * (float)c[e];
        }
    }
    float* ob = out + (size_t)b * OUT_LEN + (size_t)4096 * HOP;
    ob[tid]       = (s0 + acs) * (1.f / 1024.f);
    ob[tid + 256] = (s1 + acs) * (1.f / 1024.f);
}

// ---------- fallback (round-2 kernel, no workspace needed) ----------
#define LDBL 40
__global__ __launch_bounds__(256, 2) void istft_fused_legacy(
    const float* __restrict__ magn, const float* __restrict__ phase,
    const float* __restrict__ acv,
    const float* __restrict__ rk,  const float* __restrict__ ik,
    float* __restrict__ out)
{
    __shared__ __attribute__((aligned(16))) bf16 As[2][128 * LDBL];
    __shared__ __attribute__((aligned(16))) bf16 Bs[2][129 * LDBL];
    const int tid = threadIdx.x;
    const int w = tid >> 6, l = tid & 63;
    const int bid = blockIdx.x;
    const int xcd = bid & 7, q = bid >> 3;
    const int jt = q & 7, pgrp = q >> 3;
    const int pnl = pgrp * 8 + xcd;
    const int b = pnl / NTT33, tt0 = pnl - b * NTT33;
    const int j0 = jt * 64, t0 = tt0 * 128;
    const float* xm = magn  + (size_t)b * NFREQ * T_SZ;
    const float* xp = phase + (size_t)b * NFREQ * T_SZ;
    const int jrow = tid >> 3, fc = (tid & 7) * 4;
    const int f0 = (tid >> 5) * 4, tl = tid & 31;
    f32x4 areg[4]; float vreg[4][4]; float rz = 0.f;
    f32x4 acc[8][2];
    #pragma unroll
    for (int i = 0; i < 8; ++i)
        #pragma unroll
        for (int j = 0; j < 2; ++j) acc[i][j] = (f32x4){0.f, 0.f, 0.f, 0.f};
    const int nbase = w * 32;
    auto loadA = [&](int ks) {
        const int k0 = ks * 32;
        const float* wsrc = (k0 < NFREQ) ? (rk + k0) : (ik + (k0 - NFREQ));
        #pragma unroll
        for (int i = 0; i < 4; ++i) {
            const int jr = jrow + 32 * i;
            const int j = (jr < 64) ? (j0 + jr) : (j0 + 448 + jr);
            areg[i] = *(const f32x4*)&wsrc[(size_t)j * NFREQ + fc];
        }
    };
    auto writeA = [&](int p) {
        #pragma unroll
        for (int i = 0; i < 4; ++i) {
            bf16x4 v;
            v[0] = (bf16)areg[i][0]; v[1] = (bf16)areg[i][1];
            v[2] = (bf16)areg[i][2]; v[3] = (bf16)areg[i][3];
            *(bf16x4*)&As[p][(jrow + 32 * i) * LDBL + fc] = v;
        }
    };
    auto loadB = [&](int ks) {
        const int k0 = ks * 32;
        const float* xbp = (k0 < NFREQ) ? (xm + (size_t)k0 * T_SZ)
                                        : (xp + (size_t)(k0 - NFREQ) * T_SZ);
        #pragma unroll
        for (int i = 0; i < 4; ++i) {
            if (t0 + 32 * i + 32 <= T_SZ) {
                #pragma unroll
                for (int fj = 0; fj < 4; ++fj)
                    vreg[fj][i] = xbp[(size_t)(f0 + fj) * T_SZ + t0 + tl + 32 * i];
            } else {
                #pragma unroll
                for (int fj = 0; fj < 4; ++fj) vreg[fj][i] = 0.f;
            }
        }
        if (tid < 32) rz = (t0 >= 1) ? xbp[(size_t)tid * T_SZ + (t0 - 1)] : 0.f;
    };
    auto writeB = [&](int p) {
        #pragma unroll
        for (int i = 0; i < 4; ++i) {
            bf16x4 v;
            v[0] = (bf16)vreg[0][i]; v[1] = (bf16)vreg[1][i];
            v[2] = (bf16)vreg[2][i]; v[3] = (bf16)vreg[3][i];
            *(bf16x4*)&Bs[p][(1 + tl + 32 * i) * LDBL + f0] = v;
        }
        if (tid < 32) Bs[p][tid] = (bf16)rz;
    };
    loadA(0); loadB(0); writeA(0); writeB(0);
    __syncthreads();
    int p = 0;
    for (int ks = 0; ks < 32; ++ks) {
        if (ks + 1 < 32) { loadA(ks + 1); loadB(ks + 1); }
        bf16x8 af[8], blv[2], bhv[2];
        #pragma unroll
        for (int mi = 0; mi < 8; ++mi)
            af[mi] = *(const bf16x8*)&As[p][(mi * 16 + (l & 15)) * LDBL + (l >> 4) * 8];
        #pragma unroll
        for (int ni = 0; ni < 2; ++ni) {
            const int rb = nbase + ni * 16 + (l & 15);
            bhv[ni] = *(const bf16x8*)&Bs[p][rb * LDBL + (l >> 4) * 8];
            blv[ni] = *(const bf16x8*)&Bs[p][(rb + 1) * LDBL + (l >> 4) * 8];
        }
        #pragma unroll
        for (int ni = 0; ni < 2; ++ni)
            #pragma unroll
            for (int mi = 0; mi < 4; ++mi) {
                acc[mi][ni] = __builtin_amdgcn_mfma_f32_16x16x32_bf16(af[mi], blv[ni], acc[mi][ni], 0, 0, 0);
                acc[mi + 4][ni] = __builtin_amdgcn_mfma_f32_16x16x32_bf16(af[mi + 4], bhv[ni], acc[mi + 4][ni], 0, 0, 0);
            }
        if (ks + 1 < 32) { writeA(p ^ 1); writeB(p ^ 1); }
        __syncthreads();
        p ^= 1;
    }
    const float inv = 1.0f / 1024.0f;
    float* ob = out + (size_t)b * OUT_LEN;
    const float* acb = acv + (size_t)b * T_SZ;
    #pragma unroll
    for (int ni = 0; ni < 2; ++ni) {
        const int tt = t0 + nbase + ni * 16 + (l & 15);
        if (tt <= T_SZ) {
            float acs = 0.f;
            if (tt < T_SZ) acs += acb[tt];
            if (tt >= 1)   acs += acb[tt - 1];
            #pragma unroll
            for (int mi = 0; mi < 4; ++mi) {
                const int jl = j0 + mi * 16 + (l >> 4) * 4;
                f32x4 v;
                #pragma unroll
                for (int rr = 0; rr < 4; ++rr)
                    v[rr] = (acc[mi][ni][rr] + acc[mi + 4][ni][rr] + acs) * inv;
                __builtin_nontemporal_store(v, (f32x4*)&ob[(size_t)tt * HOP + jl]);
            }
        }
    }
}

extern "C" void kernel_launch(void* const* d_in, const int* in_sizes, int n_in,
                              void* d_out, int out_size, void* d_ws, size_t ws_size,
                              hipStream_t stream) {
    const float* magn  = (const float*)d_in[0];
    const float* phase = (const float*)d_in[1];
    const float* ac    = (const float*)d_in[2];
    const float* rk    = (const float*)d_in[3];
    const float* ik    = (const float*)d_in[4];
    float* out = (float*)d_out;

    if (ws_size >= WS_NEED) {
        bf16* Xw = (bf16*)d_ws;
        bf16* Wt = Xw + XW_ELEMS;
        cvt_w<<<1024, 256, 0, stream>>>(rk, ik, Wt);
        zpad<<<16, 128, 0, stream>>>(Xw);
        cvt_x<<<8192, 256, 0, stream>>>(magn, phase, Xw);
        istft_gemm3<<<2048, 256, 0, stream>>>(Xw, Wt, ac, out);
        istft_tail<<<16, 256, 0, stream>>>(Xw, Wt, ac, out);
    } else {
        istft_fused_legacy<<<528 * 8, 256, 0, stream>>>(magn, phase, ac, rk, ik, out);
    }
}

// Round 6
// 248.182 us; speedup vs baseline: 1.1938x; 1.0195x over previous
//
#include <hip/hip_runtime.h>
#include <hip/hip_bf16.h>

typedef __bf16 bf16;
typedef __bf16 bf16x4 __attribute__((ext_vector_type(4)));
typedef __bf16 bf16x8 __attribute__((ext_vector_type(8)));
typedef float  f32x4  __attribute__((ext_vector_type(4)));

#define T_SZ   4096
#define NFREQ  512
#define HOP    512
#define OUT_LEN 2097664   // 4097 * 512
#define NTT33  33
#define XROWS  4097       // phys rows per batch in Xw: row r holds t = r-1 (row 0 = zeros)

#define XW_ELEMS ((size_t)16 * XROWS * 1024)
#define WT_ELEMS ((size_t)1024 * 1024)
#define WS_NEED  ((XW_ELEMS + WT_ELEMS) * 2)

// 8-phase GEMM LDS: 2 x (A 512x32 + B 257x32) bf16 = 98432 B
#define AELEM 16384
#define BELEM 8224
#define LDS8  ((AELEM + BELEM) * 2 * 2)

#define SB()  __builtin_amdgcn_sched_barrier(0)
#define BAR() __builtin_amdgcn_s_barrier()

__device__ __forceinline__ void gl16(const void* g, void* l) {
    __builtin_amdgcn_global_load_lds(
        (const __attribute__((address_space(1))) void*)g,
        (__attribute__((address_space(3))) void*)l, 16, 0, 0);
}

// ---------- Wt[j][k] = k<512 ? rk[j][k] : ik[j][k-512]; blocks<16 also zero Xw row 0 ----------
__global__ __launch_bounds__(256, 4) void cvt_w(const float* __restrict__ rk,
                                                const float* __restrict__ ik,
                                                bf16* __restrict__ Wt,
                                                bf16* __restrict__ Xw) {
    const int j  = blockIdx.x;
    const int k4 = threadIdx.x * 4;
    const float* s = (k4 < NFREQ) ? &rk[j * NFREQ + k4] : &ik[j * NFREQ + k4 - NFREQ];
    f32x4 v = *(const f32x4*)s;
    bf16x4 h;
    h[0] = (bf16)v[0]; h[1] = (bf16)v[1]; h[2] = (bf16)v[2]; h[3] = (bf16)v[3];
    *(bf16x4*)&Wt[((size_t)j << 10) + k4] = h;
    if (j < 16) {   // zero phys row 0 of batch j (t = -1)
        bf16x4 z = {};
        *(bf16x4*)&Xw[(((size_t)j * XROWS) << 10) + k4] = z;
    }
}

// ---------- Xw[b][1+t][k] = (k<512?magn:phase)[b][k%512][t] ----------
__global__ __launch_bounds__(256, 4) void cvt_x(const float* __restrict__ magn,
                                                const float* __restrict__ phase,
                                                bf16* __restrict__ Xw) {
    __shared__ bf16 t2[64][132];
    const int tid = threadIdx.x;
    const int bid = blockIdx.x;
    const int kt  = bid & 15;
    const int tt  = (bid >> 4) & 31;
    const int b   = bid >> 9;
    const float* src = (kt < 8 ? magn : phase)
                     + ((size_t)b * NFREQ + (kt & 7) * 64) * T_SZ + tt * 128;
    const int fr = tid >> 5;
    const int c  = (tid & 31) * 4;
    #pragma unroll
    for (int p = 0; p < 8; ++p) {
        const int f = fr + 8 * p;
        f32x4 v = *(const f32x4*)&src[(size_t)f * T_SZ + c];
        bf16x4 h;
        h[0] = (bf16)v[0]; h[1] = (bf16)v[1]; h[2] = (bf16)v[2]; h[3] = (bf16)v[3];
        *(bf16x4*)&t2[f][c] = h;
    }
    __syncthreads();
    const int koff = (tid & 7) * 8;
    bf16* dstb = Xw + (((size_t)b * XROWS + 1 + tt * 128) << 10) + kt * 64 + koff;
    #pragma unroll
    for (int q = 0; q < 4; ++q) {
        const int tr = (tid >> 3) + 32 * q;
        bf16x8 o;
        #pragma unroll
        for (int ki = 0; ki < 8; ++ki) o[ki] = t2[koff + ki][tr];
        *(bf16x8*)&dstb[(size_t)tr << 10] = o;
    }
}

// ---------- 8-phase fused GEMM: 256jl x 256tt tile, 8 waves, counted vmcnt ----------
// A-tile rows 0..255 = Wt[j0+r] (lo), 256..511 = Wt[j0+256+r] (hi).
// B-tile row r (0..256) = X[t0-1+r] = phys Xw row xb+t0+r (always valid).
// Swizzle both-sides: 16B slot' = slot ^ ((row ^ row>>2)&3); LDS dest linear,
// gl16 SOURCE pre-swizzled, ds_read applies the same XOR.
// Per K-step (BK=32): 4 phases x {stage freed region; ds_reads; lgkm0; prio1; 16 MFMA; prio0; bar}.
// vmcnt(7) between K-steps (one K-tile = 7 gl16/wave in flight), vmcnt(0) only at the last.
__global__ __launch_bounds__(512, 2) void istft_gemm8(
    const bf16* __restrict__ Xw, const bf16* __restrict__ Wt,
    const float* __restrict__ acv, float* __restrict__ out)
{
    extern __shared__ __attribute__((aligned(16))) bf16 lds[];
    bf16* A0 = lds;
    bf16* B0 = lds + AELEM;
    bf16* A1 = lds + AELEM + BELEM;
    bf16* B1 = lds + 2 * AELEM + BELEM;

    const int tid = threadIdx.x;
    const int w   = tid >> 6;         // 8 waves: wr = w>>2 (jl half), wc = w&3 (tt quarter)
    const int l   = tid & 63;
    const int wr  = w >> 2, wc = w & 3;
    const int c15 = l & 15, c4 = l >> 4;

    const int bid = blockIdx.x;       // 512 = 256 panels x 2 jt; panel -> xcd = bid&7
    const int xcd = bid & 7;
    const int idx = bid >> 3;         // 0..63
    const int jt  = idx & 1;
    const int pnl = (idx >> 1) * 8 + xcd;   // 0..255
    const int b   = pnl >> 4;
    const int tt0 = pnl & 15;
    const int j0  = jt * 256;
    const int t0  = tt0 * 256;
    const size_t xb = (size_t)b * XROWS;

    // staging: 64B rows, 4 slots; per sweep wave w covers rows 16w..16w+15
    const int srow = 16 * w + (l >> 2);                                // 0..127
    const int ssrc = ((l & 3) ^ ((l >> 2) & 3) ^ ((l >> 4) & 3)) * 8;  // pre-swizzled src slot
    size_t agj[4];
    #pragma unroll
    for (int i = 0; i < 4; ++i) {
        const int r  = 128 * i + srow;                  // A-tile row
        const int gj = (r < 256) ? (j0 + r) : (j0 + 256 + r);
        agj[i] = ((size_t)gj << 10);
    }
    const size_t bsrc0 = (xb + t0 + srow) << 10;        // B rows 0..127
    const size_t bsrc1 = (xb + t0 + 128 + srow) << 10;  // B rows 128..255
    const size_t bsrcX = (xb + t0 + 256) << 10;         // B row 256 (g=0: linear)

    auto stageAlo = [&](bf16* Ab, int ks) {
        const int k0 = ks * 32;
        gl16(Wt + agj[0] + k0 + ssrc, Ab + (16 * w) * 32);
        gl16(Wt + agj[1] + k0 + ssrc, Ab + (128 + 16 * w) * 32);
    };
    auto stageAhi = [&](bf16* Ab, int ks) {
        const int k0 = ks * 32;
        gl16(Wt + agj[2] + k0 + ssrc, Ab + (256 + 16 * w) * 32);
        gl16(Wt + agj[3] + k0 + ssrc, Ab + (384 + 16 * w) * 32);
    };
    auto stageB = [&](bf16* Bb, int ks) {     // 3 issues/wave (row-256 load redundant x8, benign)
        const int k0 = ks * 32;
        gl16(Xw + bsrc0 + k0 + ssrc, Bb + (16 * w) * 32);
        gl16(Xw + bsrc1 + k0 + ssrc, Bb + (128 + 16 * w) * 32);
        if (l < 4) gl16(Xw + bsrcX + k0 + l * 8, Bb + 256 * 32);
    };

    f32x4 acc[8][4];
    #pragma unroll
    for (int i = 0; i < 8; ++i)
        #pragma unroll
        for (int j = 0; j < 4; ++j)
            acc[i][j] = (f32x4){0.f, 0.f, 0.f, 0.f};

    // frag readers (swizzled)
    auto rdA = [&](const bf16* Ab, int mb, int hi, bf16x8* d) {
        #pragma unroll
        for (int mi = 0; mi < 4; ++mi) {
            const int r = wr * 128 + (mb + mi) * 16 + c15;      // 0..255
            const int s = ((c4 ^ r ^ (r >> 2)) & 3) * 8;
            d[mi] = *(const bf16x8*)&Ab[(r + (hi ? 256 : 0)) * 32 + s];
        }
    };
    auto rdBlo = [&](const bf16* Bb, bf16x8* d) {       // t = tt  (rows 1..256)
        #pragma unroll
        for (int n = 0; n < 4; ++n) {
            const int r = wc * 64 + n * 16 + c15 + 1;
            const int s = ((c4 ^ r ^ (r >> 2)) & 3) * 8;
            d[n] = *(const bf16x8*)&Bb[r * 32 + s];
        }
    };
    auto rdBhi = [&](const bf16* Bb, bf16x8* d) {       // t = tt-1 (rows 0..255)
        #pragma unroll
        for (int n = 0; n < 4; ++n) {
            const int r = wc * 64 + n * 16 + c15;
            const int s = ((c4 ^ r ^ (r >> 2)) & 3) * 8;
            d[n] = *(const bf16x8*)&Bb[r * 32 + s];
        }
    };

    // prologue: tiles 0 and 1
    stageAlo(A0, 0); stageB(B0, 0); stageAhi(A0, 0);
    stageAlo(A1, 1); stageB(B1, 1); stageAhi(A1, 1);

    bf16x8 a[4], bl[4], bh[4];

    for (int it = 0; it < 16; ++it) {
        #pragma unroll
        for (int s2 = 0; s2 < 2; ++s2) {
            const int ks = 2 * it + s2;
            bf16* Ab = s2 ? A1 : A0;
            bf16* Bb = s2 ? B1 : B0;
            const bool st = (it < 15);

            if (it == 15 && s2 == 1) asm volatile("s_waitcnt vmcnt(0)" ::: "memory");
            else                     asm volatile("s_waitcnt vmcnt(7)" ::: "memory");
            SB(); BAR(); SB();

            // ---- Ph1: lo m0-3 ----
            rdA(Ab, 0, 0, a); rdBlo(Bb, bl);
            asm volatile("s_waitcnt lgkmcnt(0)" ::: "memory"); SB();
            __builtin_amdgcn_s_setprio(1);
            #pragma unroll
            for (int m = 0; m < 4; ++m)
                #pragma unroll
                for (int n = 0; n < 4; ++n)
                    acc[m][n] = __builtin_amdgcn_mfma_f32_16x16x32_bf16(a[m], bl[n], acc[m][n], 0, 0, 0);
            __builtin_amdgcn_s_setprio(0);
            SB(); BAR(); SB();

            // ---- Ph2: lo m4-7 ----
            rdA(Ab, 4, 0, a);
            asm volatile("s_waitcnt lgkmcnt(0)" ::: "memory"); SB();
            __builtin_amdgcn_s_setprio(1);
            #pragma unroll
            for (int m = 0; m < 4; ++m)
                #pragma unroll
                for (int n = 0; n < 4; ++n)
                    acc[4 + m][n] = __builtin_amdgcn_mfma_f32_16x16x32_bf16(a[m], bl[n], acc[4 + m][n], 0, 0, 0);
            __builtin_amdgcn_s_setprio(0);
            SB(); BAR(); SB();          // A-lo of buf fully read by all waves

            // ---- Ph3: hi m0-3 ----
            if (st) stageAlo(Ab, ks + 2);
            rdA(Ab, 0, 1, a); rdBhi(Bb, bh);
            asm volatile("s_waitcnt lgkmcnt(0)" ::: "memory"); SB();
            __builtin_amdgcn_s_setprio(1);
            #pragma unroll
            for (int m = 0; m < 4; ++m)
                #pragma unroll
                for (int n = 0; n < 4; ++n)
                    acc[m][n] = __builtin_amdgcn_mfma_f32_16x16x32_bf16(a[m], bh[n], acc[m][n], 0, 0, 0);
            __builtin_amdgcn_s_setprio(0);
            SB(); BAR(); SB();          // B of buf fully read (Blo@Ph1, Bhi@Ph3)

            // ---- Ph4: hi m4-7 ----
            if (st) stageB(Bb, ks + 2);
            rdA(Ab, 4, 1, a);
            asm volatile("s_waitcnt lgkmcnt(0)" ::: "memory"); SB();
            __builtin_amdgcn_s_setprio(1);
            #pragma unroll
            for (int m = 0; m < 4; ++m)
                #pragma unroll
                for (int n = 0; n < 4; ++n)
                    acc[4 + m][n] = __builtin_amdgcn_mfma_f32_16x16x32_bf16(a[m], bh[n], acc[4 + m][n], 0, 0, 0);
            __builtin_amdgcn_s_setprio(0);
            SB(); BAR(); SB();          // A-hi of buf fully read
            if (st) stageAhi(Ab, ks + 2);
        }
    }

    // epilogue: out[tt*512+jl] = (lo + hi + ac[tt] + ac[tt-1]) / 1024
    const float inv = 1.0f / 1024.0f;
    float* ob = out + (size_t)b * OUT_LEN;
    const float* acb = acv + (size_t)b * T_SZ;
    const int jbase = j0 + wr * 128 + c4 * 4;
    #pragma unroll
    for (int n = 0; n < 4; ++n) {
        const int tt = t0 + wc * 64 + n * 16 + c15;          // 0..4095
        const float acs = acb[tt] + (tt ? acb[tt - 1] : 0.f);
        #pragma unroll
        for (int m = 0; m < 8; ++m) {
            f32x4 v;
            #pragma unroll
            for (int rr = 0; rr < 4; ++rr)
                v[rr] = (acc[m][n][rr] + acs) * inv;
            __builtin_nontemporal_store(v, (f32x4*)&ob[(size_t)tt * HOP + jbase + m * 16]);
        }
    }
}

// ---------- tail: out column t=4096 (hi term only) ----------
__global__ __launch_bounds__(256, 2) void istft_tail(
    const bf16* __restrict__ Xw, const bf16* __restrict__ Wt,
    const float* __restrict__ acv, float* __restrict__ out)
{
    __shared__ float xf[1024];
    const int b = blockIdx.x, tid = threadIdx.x;
    const bf16* xr = Xw + (((size_t)b * XROWS + 4096) << 10);   // t = 4095
    {
        bf16x4 v = *(const bf16x4*)&xr[tid * 4];
        xf[tid * 4 + 0] = (float)v[0]; xf[tid * 4 + 1] = (float)v[1];
        xf[tid * 4 + 2] = (float)v[2]; xf[tid * 4 + 3] = (float)v[3];
    }
    __syncthreads();
    const float acs = acv[b * T_SZ + 4095];
    float s0 = 0.f, s1 = 0.f;
    const bf16* w0 = Wt + ((size_t)(512 + tid) << 10);
    const bf16* w1 = w0 + ((size_t)256 << 10);
    for (int kc = 0; kc < 128; ++kc) {
        bf16x8 av = *(const bf16x8*)&w0[kc * 8];
        bf16x8 cv = *(const bf16x8*)&w1[kc * 8];
        #pragma unroll
        for (int e = 0; e < 8; ++e) {
            const float xv = xf[kc * 8 + e];
            s0 += xv * (float)av[e];
            s1 += xv * (float)cv[e];
        }
    }
    float* ob = out + (size_t)b * OUT_LEN + (size_t)4096 * HOP;
    ob[tid]       = (s0 + acs) * (1.f / 1024.f);
    ob[tid + 256] = (s1 + acs) * (1.f / 1024.f);
}

// ---------- fallback (round-2 kernel, no workspace needed) ----------
#define LDBL 40
__global__ __launch_bounds__(256, 2) void istft_fused_legacy(
    const float* __restrict__ magn, const float* __restrict__ phase,
    const float* __restrict__ acv,
    const float* __restrict__ rk,  const float* __restrict__ ik,
    float* __restrict__ out)
{
    __shared__ __attribute__((aligned(16))) bf16 As[2][128 * LDBL];
    __shared__ __attribute__((aligned(16))) bf16 Bs[2][129 * LDBL];
    const int tid = threadIdx.x;
    const int w = tid >> 6, l = tid & 63;
    const int bid = blockIdx.x;
    const int xcd = bid & 7, q = bid >> 3;
    const int jt = q & 7, pgrp = q >> 3;
    const int pnl = pgrp * 8 + xcd;
    const int b = pnl / NTT33, tt0 = pnl - b * NTT33;
    const int j0 = jt * 64, t0 = tt0 * 128;
    const float* xm = magn  + (size_t)b * NFREQ * T_SZ;
    const float* xp = phase + (size_t)b * NFREQ * T_SZ;
    const int jrow = tid >> 3, fc = (tid & 7) * 4;
    const int f0 = (tid >> 5) * 4, tl = tid & 31;
    f32x4 areg[4]; float vreg[4][4]; float rz = 0.f;
    f32x4 acc[8][2];
    #pragma unroll
    for (int i = 0; i < 8; ++i)
        #pragma unroll
        for (int j = 0; j < 2; ++j) acc[i][j] = (f32x4){0.f, 0.f, 0.f, 0.f};
    const int nbase = w * 32;
    auto loadA = [&](int ks) {
        const int k0 = ks * 32;
        const float* wsrc = (k0 < NFREQ) ? (rk + k0) : (ik + (k0 - NFREQ));
        #pragma unroll
        for (int i = 0; i < 4; ++i) {
            const int jr = jrow + 32 * i;
            const int j = (jr < 64) ? (j0 + jr) : (j0 + 448 + jr);
            areg[i] = *(const f32x4*)&wsrc[(size_t)j * NFREQ + fc];
        }
    };
    auto writeA = [&](int p) {
        #pragma unroll
        for (int i = 0; i < 4; ++i) {
            bf16x4 v;
            v[0] = (bf16)areg[i][0]; v[1] = (bf16)areg[i][1];
            v[2] = (bf16)areg[i][2]; v[3] = (bf16)areg[i][3];
            *(bf16x4*)&As[p][(jrow + 32 * i) * LDBL + fc] = v;
        }
    };
    auto loadB = [&](int ks) {
        const int k0 = ks * 32;
        const float* xbp = (k0 < NFREQ) ? (xm + (size_t)k0 * T_SZ)
                                        : (xp + (size_t)(k0 - NFREQ) * T_SZ);
        #pragma unroll
        for (int i = 0; i < 4; ++i) {
            if (t0 + 32 * i + 32 <= T_SZ) {
                #pragma unroll
                for (int fj = 0; fj < 4; ++fj)
                    vreg[fj][i] = xbp[(size_t)(f0 + fj) * T_SZ + t0 + tl + 32 * i];
            } else {
                #pragma unroll
                for (int fj = 0; fj < 4; ++fj) vreg[fj][i] = 0.f;
            }
        }
        if (tid < 32) rz = (t0 >= 1) ? xbp[(size_t)tid * T_SZ + (t0 - 1)] : 0.f;
    };
    auto writeB = [&](int p) {
        #pragma unroll
        for (int i = 0; i < 4; ++i) {
            bf16x4 v;
            v[0] = (bf16)vreg[0][i]; v[1] = (bf16)vreg[1][i];
            v[2] = (bf16)vreg[2][i]; v[3] = (bf16)vreg[3][i];
            *(bf16x4*)&Bs[p][(1 + tl + 32 * i) * LDBL + f0] = v;
        }
        if (tid < 32) Bs[p][tid] = (bf16)rz;
    };
    loadA(0); loadB(0); writeA(0); writeB(0);
    __syncthreads();
    int p = 0;
    for (int ks = 0; ks < 32; ++ks) {
        if (ks + 1 < 32) { loadA(ks + 1); loadB(ks + 1); }
        bf16x8 af[8], blv[2], bhv[2];
        #pragma unroll
        for (int mi = 0; mi < 8; ++mi)
            af[mi] = *(const bf16x8*)&As[p][(mi * 16 + (l & 15)) * LDBL + (l >> 4) * 8];
        #pragma unroll
        for (int ni = 0; ni < 2; ++ni) {
            const int rb = nbase + ni * 16 + (l & 15);
            bhv[ni] = *(const bf16x8*)&Bs[p][rb * LDBL + (l >> 4) * 8];
            blv[ni] = *(const bf16x8*)&Bs[p][(rb + 1) * LDBL + (l >> 4) * 8];
        }
        #pragma unroll
        for (int ni = 0; ni < 2; ++ni)
            #pragma unroll
            for (int mi = 0; mi < 4; ++mi) {
                acc[mi][ni] = __builtin_amdgcn_mfma_f32_16x16x32_bf16(af[mi], blv[ni], acc[mi][ni], 0, 0, 0);
                acc[mi + 4][ni] = __builtin_amdgcn_mfma_f32_16x16x32_bf16(af[mi + 4], bhv[ni], acc[mi + 4][ni], 0, 0, 0);
            }
        if (ks + 1 < 32) { writeA(p ^ 1); writeB(p ^ 1); }
        __syncthreads();
        p ^= 1;
    }
    const float inv = 1.0f / 1024.0f;
    float* ob = out + (size_t)b * OUT_LEN;
    const float* acb = acv + (size_t)b * T_SZ;
    #pragma unroll
    for (int ni = 0; ni < 2; ++ni) {
        const int tt = t0 + nbase + ni * 16 + (l & 15);
        if (tt <= T_SZ) {
            float acs = 0.f;
            if (tt < T_SZ) acs += acb[tt];
            if (tt >= 1)   acs += acb[tt - 1];
            #pragma unroll
            for (int mi = 0; mi < 4; ++mi) {
                const int jl = j0 + mi * 16 + (l >> 4) * 4;
                f32x4 v;
                #pragma unroll
                for (int rr = 0; rr < 4; ++rr)
                    v[rr] = (acc[mi][ni][rr] + acc[mi + 4][ni][rr] + acs) * inv;
                __builtin_nontemporal_store(v, (f32x4*)&ob[(size_t)tt * HOP + jl]);
            }
        }
    }
}

extern "C" void kernel_launch(void* const* d_in, const int* in_sizes, int n_in,
                              void* d_out, int out_size, void* d_ws, size_t ws_size,
                              hipStream_t stream) {
    const float* magn  = (const float*)d_in[0];
    const float* phase = (const float*)d_in[1];
    const float* ac    = (const float*)d_in[2];
    const float* rk    = (const float*)d_in[3];
    const float* ik    = (const float*)d_in[4];
    float* out = (float*)d_out;

    bool ok = (ws_size >= WS_NEED);
    if (ok) {
        static bool attr_done = false;   // attribute is idempotent; safe under capture? set every call
        if (hipFuncSetAttribute((const void*)istft_gemm8,
                hipFuncAttributeMaxDynamicSharedMemorySize, LDS8) != hipSuccess)
            ok = false;
        (void)attr_done;
    }
    if (ok) {
        bf16* Xw = (bf16*)d_ws;
        bf16* Wt = Xw + XW_ELEMS;
        cvt_w<<<1024, 256, 0, stream>>>(rk, ik, Wt, Xw);
        cvt_x<<<8192, 256, 0, stream>>>(magn, phase, Xw);
        istft_gemm8<<<512, 512, LDS8, stream>>>(Xw, Wt, ac, out);
        istft_tail<<<16, 256, 0, stream>>>(Xw, Wt, ac, out);
    } else {
        istft_fused_legacy<<<528 * 8, 256, 0, stream>>>(magn, phase, ac, rk, ik, out);
    }
}

// Round 7
// 244.275 us; speedup vs baseline: 1.2129x; 1.0160x over previous
//
#include <hip/hip_runtime.h>
#include <hip/hip_bf16.h>

typedef __bf16 bf16;
typedef __bf16 bf16x4 __attribute__((ext_vector_type(4)));
typedef __bf16 bf16x8 __attribute__((ext_vector_type(8)));
typedef float  f32x4  __attribute__((ext_vector_type(4)));

#define T_SZ   4096
#define NFREQ  512
#define HOP    512
#define OUT_LEN 2097664   // 4097 * 512
#define NTT33  33
#define XROWS  4097       // phys rows per batch in Xw: row r holds t = r-1 (row 0 = zeros)

#define XW_ELEMS ((size_t)16 * XROWS * 1024)
#define WT_ELEMS ((size_t)1024 * 1024)
#define WS_NEED  ((XW_ELEMS + WT_ELEMS) * 2)

#define SB()  __builtin_amdgcn_sched_barrier(0)
#define BAR() __builtin_amdgcn_s_barrier()

__device__ __forceinline__ void gl16(const void* g, void* l) {
    __builtin_amdgcn_global_load_lds(
        (const __attribute__((address_space(1))) void*)g,
        (__attribute__((address_space(3))) void*)l, 16, 0, 0);
}

// ---------- Wt[j][k] = k<512 ? rk[j][k] : ik[j][k-512]; blocks<16 also zero Xw row 0 ----------
__global__ __launch_bounds__(256, 4) void cvt_w(const float* __restrict__ rk,
                                                const float* __restrict__ ik,
                                                bf16* __restrict__ Wt,
                                                bf16* __restrict__ Xw) {
    const int j  = blockIdx.x;
    const int k4 = threadIdx.x * 4;
    const float* s = (k4 < NFREQ) ? &rk[j * NFREQ + k4] : &ik[j * NFREQ + k4 - NFREQ];
    f32x4 v = *(const f32x4*)s;
    bf16x4 h;
    h[0] = (bf16)v[0]; h[1] = (bf16)v[1]; h[2] = (bf16)v[2]; h[3] = (bf16)v[3];
    *(bf16x4*)&Wt[((size_t)j << 10) + k4] = h;
    if (j < 16) {   // zero phys row 0 of batch j (t = -1)
        bf16x4 z = {};
        *(bf16x4*)&Xw[(((size_t)j * XROWS) << 10) + k4] = z;
    }
}

// ---------- Xw[b][1+t][k] = (k<512?magn:phase)[b][k%512][t] ----------
__global__ __launch_bounds__(256, 4) void cvt_x(const float* __restrict__ magn,
                                                const float* __restrict__ phase,
                                                bf16* __restrict__ Xw) {
    __shared__ bf16 t2[64][132];
    const int tid = threadIdx.x;
    const int bid = blockIdx.x;
    const int kt  = bid & 15;
    const int tt  = (bid >> 4) & 31;
    const int b   = bid >> 9;
    const float* src = (kt < 8 ? magn : phase)
                     + ((size_t)b * NFREQ + (kt & 7) * 64) * T_SZ + tt * 128;
    const int fr = tid >> 5;
    const int c  = (tid & 31) * 4;
    #pragma unroll
    for (int p = 0; p < 8; ++p) {
        const int f = fr + 8 * p;
        f32x4 v = *(const f32x4*)&src[(size_t)f * T_SZ + c];
        bf16x4 h;
        h[0] = (bf16)v[0]; h[1] = (bf16)v[1]; h[2] = (bf16)v[2]; h[3] = (bf16)v[3];
        *(bf16x4*)&t2[f][c] = h;
    }
    __syncthreads();
    const int koff = (tid & 7) * 8;
    bf16* dstb = Xw + (((size_t)b * XROWS + 1 + tt * 128) << 10) + kt * 64 + koff;
    #pragma unroll
    for (int q = 0; q < 4; ++q) {
        const int tr = (tid >> 3) + 32 * q;
        bf16x8 o;
        #pragma unroll
        for (int ki = 0; ki < 8; ++ki) o[ki] = t2[koff + ki][tr];
        *(bf16x8*)&dstb[(size_t)tr << 10] = o;
    }
}

// ---------- main GEMM: 128j x 128t tile, 4 waves, 3 blocks/CU, 2-phase counted-vmcnt ----------
// A-tile rows 0..127 = Wt[j0+r] (lo), 128..255 = Wt[j0+512+(r-128)] (hi).
// B-tile row r (0..128) = X[t0-1+r] = phys Xw row t0+r (always valid).
// Swizzle both-sides: 16B slot' = slot ^ ((row ^ row>>2)&3); LDS linear dest,
// gl16 SOURCE pre-swizzled, ds_read applies the same XOR.
// Per K-step, m201 phase order:
//  Ph_A: rd Alo+Blo(cur); stage Ahi+B(ks+1 -> other buf); BAR; lgkm0; prio1; 16 MFMA; prio0
//  Ph_B: rd Ahi+Bhi(cur); stage Alo(ks+2 -> cur buf); vmcnt(2); BAR; lgkm0; prio1; 16 MFMA; prio0
// vmcnt(2) leaves only the just-issued Alo in flight -> loads never drain in the main loop.
__global__ __launch_bounds__(256, 3) void istft_gemm4(
    const bf16* __restrict__ Xw, const bf16* __restrict__ Wt,
    const float* __restrict__ acv, float* __restrict__ out)
{
    __shared__ __attribute__((aligned(16))) bf16 As[2][256 * 32];
    __shared__ __attribute__((aligned(16))) bf16 Bs[2][129 * 32];

    const int tid = threadIdx.x;
    const int w   = tid >> 6;      // 4 waves: wr = w>>1 (j half), wc = w&1 (t half)
    const int l   = tid & 63;

    const int bid = blockIdx.x;    // 2048 = 512 panels x 4 j-tiles; panel -> xcd = bid&7
    const int xcd = bid & 7;
    const int jt  = (bid >> 3) & 3;
    const int pg  = bid >> 5;      // 0..63
    const int pnl = pg * 8 + xcd;  // 0..511
    const int b   = pnl >> 5;
    const int tt0 = pnl & 31;
    const int j0  = jt * 128;
    const int t0  = tt0 * 128;

    // staging map: 64B rows of 4 slots; lane -> row chunk+(l>>2), slot l&3
    const int ssrc = ((l & 3) ^ ((l >> 2) & 3) ^ ((l >> 4) & 3)) * 8;  // pre-swizzled src slot
    const int arow = 16 * w + (l >> 2);                                // 0..63 per sweep
    const size_t xb = (size_t)b * XROWS;

    size_t agj[4];
    #pragma unroll
    for (int i = 0; i < 4; ++i) {
        const int r  = 64 * i + arow;                       // A-tile row 0..255
        const int gj = (r < 128) ? (j0 + r) : (j0 + 384 + r);
        agj[i] = ((size_t)gj << 10);
    }
    const size_t bsrc0 = (xb + t0 + arow) << 10;            // B rows 0..63
    const size_t bsrc1 = (xb + t0 + 64 + arow) << 10;       // B rows 64..127
    const size_t bsrcX = (xb + t0 + 128) << 10;             // B row 128 (g(128)=0: linear)

    auto stageAlo = [&](int p, int ks) {
        const int k0 = ks * 32;
        gl16(Wt + agj[0] + k0 + ssrc, &As[p][(16 * w) * 32]);
        gl16(Wt + agj[1] + k0 + ssrc, &As[p][(64 + 16 * w) * 32]);
    };
    auto stageAhi = [&](int p, int ks) {
        const int k0 = ks * 32;
        gl16(Wt + agj[2] + k0 + ssrc, &As[p][(128 + 16 * w) * 32]);
        gl16(Wt + agj[3] + k0 + ssrc, &As[p][(192 + 16 * w) * 32]);
    };
    auto stageB = [&](int p, int ks) {
        const int k0 = ks * 32;
        gl16(Xw + bsrc0 + k0 + ssrc, &Bs[p][(16 * w) * 32]);
        gl16(Xw + bsrc1 + k0 + ssrc, &Bs[p][(64 + 16 * w) * 32]);
        // all 4 waves issue (redundant same-dest write) -> uniform 7 gl16/wave/K-step
        if (l < 4) gl16(Xw + bsrcX + k0 + l * 8, &Bs[p][128 * 32]);
    };

    f32x4 acc[4][4];
    #pragma unroll
    for (int i = 0; i < 4; ++i)
        #pragma unroll
        for (int j = 0; j < 4; ++j)
            acc[i][j] = (f32x4){0.f, 0.f, 0.f, 0.f};

    const int wr = w >> 1, wc = w & 1;
    const int c15 = l & 15, c4 = l >> 4;

    bf16x8 a[4], bb[4];
    auto rdAlo = [&](int p) {
        #pragma unroll
        for (int m = 0; m < 4; ++m) {
            const int r = wr * 64 + m * 16 + c15;            // 0..127
            const int s = ((c4 ^ r ^ (r >> 2)) & 3) * 8;
            a[m] = *(const bf16x8*)&As[p][r * 32 + s];
        }
    };
    auto rdAhi = [&](int p) {
        #pragma unroll
        for (int m = 0; m < 4; ++m) {
            const int r = wr * 64 + m * 16 + c15;
            const int s = ((c4 ^ r ^ (r >> 2)) & 3) * 8;     // same XOR for r+128
            a[m] = *(const bf16x8*)&As[p][(r + 128) * 32 + s];
        }
    };
    auto rdBlo = [&](int p) {                                // t = tt (rows 1..128)
        #pragma unroll
        for (int n = 0; n < 4; ++n) {
            const int r = wc * 64 + n * 16 + c15 + 1;
            const int s = ((c4 ^ r ^ (r >> 2)) & 3) * 8;
            bb[n] = *(const bf16x8*)&Bs[p][r * 32 + s];
        }
    };
    auto rdBhi = [&](int p) {                                // t = tt-1 (rows 0..127)
        #pragma unroll
        for (int n = 0; n < 4; ++n) {
            const int r = wc * 64 + n * 16 + c15;
            const int s = ((c4 ^ r ^ (r >> 2)) & 3) * 8;
            bb[n] = *(const bf16x8*)&Bs[p][r * 32 + s];
        }
    };

    // prologue: tile0 full + tile1 Alo; retire tile0 (vmcnt leaves the 2 Alo(1) loads)
    stageAlo(0, 0); stageAhi(0, 0); stageB(0, 0);
    stageAlo(1, 1);
    asm volatile("s_waitcnt vmcnt(2)" ::: "memory");
    SB(); BAR(); SB();

    for (int ks = 0; ks < 32; ++ks) {
        const int P = ks & 1;

        // ---- Phase A: lo GEMM ----
        rdAlo(P); rdBlo(P);
        if (ks + 1 < 32) { stageAhi(P ^ 1, ks + 1); stageB(P ^ 1, ks + 1); }
        SB(); BAR();
        asm volatile("s_waitcnt lgkmcnt(0)" ::: "memory"); SB();
        __builtin_amdgcn_s_setprio(1);
        #pragma unroll
        for (int m = 0; m < 4; ++m)
            #pragma unroll
            for (int n = 0; n < 4; ++n)
                acc[m][n] = __builtin_amdgcn_mfma_f32_16x16x32_bf16(a[m], bb[n], acc[m][n], 0, 0, 0);
        __builtin_amdgcn_s_setprio(0);

        // ---- Phase B: hi GEMM ----
        rdAhi(P); rdBhi(P);
        if (ks + 2 < 32) stageAlo(P, ks + 2);
        if (ks < 30) asm volatile("s_waitcnt vmcnt(2)" ::: "memory");
        else         asm volatile("s_waitcnt vmcnt(0)" ::: "memory");
        SB(); BAR();
        asm volatile("s_waitcnt lgkmcnt(0)" ::: "memory"); SB();
        __builtin_amdgcn_s_setprio(1);
        #pragma unroll
        for (int m = 0; m < 4; ++m)
            #pragma unroll
            for (int n = 0; n < 4; ++n)
                acc[m][n] = __builtin_amdgcn_mfma_f32_16x16x32_bf16(a[m], bb[n], acc[m][n], 0, 0, 0);
        __builtin_amdgcn_s_setprio(0);
    }

    // epilogue: out[tt*512+jl] = (lo + hi + ac[tt] + ac[tt-1]) / 1024
    const float inv = 1.0f / 1024.0f;
    float* ob = out + (size_t)b * OUT_LEN;
    const float* acb = acv + (size_t)b * T_SZ;
    const int jbase = j0 + wr * 64 + c4 * 4;
    #pragma unroll
    for (int n = 0; n < 4; ++n) {
        const int tt = t0 + wc * 64 + n * 16 + c15;          // <= 4095 always
        const float acs = acb[tt] + (tt ? acb[tt - 1] : 0.f);
        #pragma unroll
        for (int m = 0; m < 4; ++m) {
            f32x4 v;
            #pragma unroll
            for (int rr = 0; rr < 4; ++rr)
                v[rr] = (acc[m][n][rr] + acs) * inv;
            __builtin_nontemporal_store(v, (f32x4*)&ob[(size_t)tt * HOP + jbase + m * 16]);
        }
    }
}

// ---------- tail: out column t=4096 (hi term only) ----------
__global__ __launch_bounds__(256, 2) void istft_tail(
    const bf16* __restrict__ Xw, const bf16* __restrict__ Wt,
    const float* __restrict__ acv, float* __restrict__ out)
{
    __shared__ float xf[1024];
    const int b = blockIdx.x, tid = threadIdx.x;
    const bf16* xr = Xw + (((size_t)b * XROWS + 4096) << 10);   // t = 4095
    {
        bf16x4 v = *(const bf16x4*)&xr[tid * 4];
        xf[tid * 4 + 0] = (float)v[0]; xf[tid * 4 + 1] = (float)v[1];
        xf[tid * 4 + 2] = (float)v[2]; xf[tid * 4 + 3] = (float)v[3];
    }
    __syncthreads();
    const float acs = acv[b * T_SZ + 4095];
    float s0 = 0.f, s1 = 0.f;
    const bf16* w0 = Wt + ((size_t)(512 + tid) << 10);
    const bf16* w1 = w0 + ((size_t)256 << 10);
    for (int kc = 0; kc < 128; ++kc) {
        bf16x8 av = *(const bf16x8*)&w0[kc * 8];
        bf16x8 cv = *(const bf16x8*)&w1[kc * 8];
        #pragma unroll
        for (int e = 0; e < 8; ++e) {
            const float xv = xf[kc * 8 + e];
            s0 += xv * (float)av[e];
            s1 += xv * (float)cv[e];
        }
    }
    float* ob = out + (size_t)b * OUT_LEN + (size_t)4096 * HOP;
    ob[tid]       = (s0 + acs) * (1.f / 1024.f);
    ob[tid + 256] = (s1 + acs) * (1.f / 1024.f);
}

// ---------- fallback (round-2 kernel, no workspace needed) ----------
#define LDBL 40
__global__ __launch_bounds__(256, 2) void istft_fused_legacy(
    const float* __restrict__ magn, const float* __restrict__ phase,
    const float* __restrict__ acv,
    const float* __restrict__ rk,  const float* __restrict__ ik,
    float* __restrict__ out)
{
    __shared__ __attribute__((aligned(16))) bf16 As[2][128 * LDBL];
    __shared__ __attribute__((aligned(16))) bf16 Bs[2][129 * LDBL];
    const int tid = threadIdx.x;
    const int w = tid >> 6, l = tid & 63;
    const int bid = blockIdx.x;
    const int xcd = bid & 7, q = bid >> 3;
    const int jt = q & 7, pgrp = q >> 3;
    const int pnl = pgrp * 8 + xcd;
    const int b = pnl / NTT33, tt0 = pnl - b * NTT33;
    const int j0 = jt * 64, t0 = tt0 * 128;
    const float* xm = magn  + (size_t)b * NFREQ * T_SZ;
    const float* xp = phase + (size_t)b * NFREQ * T_SZ;
    const int jrow = tid >> 3, fc = (tid & 7) * 4;
    const int f0 = (tid >> 5) * 4, tl = tid & 31;
    f32x4 areg[4]; float vreg[4][4]; float rz = 0.f;
    f32x4 acc[8][2];
    #pragma unroll
    for (int i = 0; i < 8; ++i)
        #pragma unroll
        for (int j = 0; j < 2; ++j) acc[i][j] = (f32x4){0.f, 0.f, 0.f, 0.f};
    const int nbase = w * 32;
    auto loadA = [&](int ks) {
        const int k0 = ks * 32;
        const float* wsrc = (k0 < NFREQ) ? (rk + k0) : (ik + (k0 - NFREQ));
        #pragma unroll
        for (int i = 0; i < 4; ++i) {
            const int jr = jrow + 32 * i;
            const int j = (jr < 64) ? (j0 + jr) : (j0 + 448 + jr);
            areg[i] = *(const f32x4*)&wsrc[(size_t)j * NFREQ + fc];
        }
    };
    auto writeA = [&](int p) {
        #pragma unroll
        for (int i = 0; i < 4; ++i) {
            bf16x4 v;
            v[0] = (bf16)areg[i][0]; v[1] = (bf16)areg[i][1];
            v[2] = (bf16)areg[i][2]; v[3] = (bf16)areg[i][3];
            *(bf16x4*)&As[p][(jrow + 32 * i) * LDBL + fc] = v;
        }
    };
    auto loadB = [&](int ks) {
        const int k0 = ks * 32;
        const float* xbp = (k0 < NFREQ) ? (xm + (size_t)k0 * T_SZ)
                                        : (xp + (size_t)(k0 - NFREQ) * T_SZ);
        #pragma unroll
        for (int i = 0; i < 4; ++i) {
            if (t0 + 32 * i + 32 <= T_SZ) {
                #pragma unroll
                for (int fj = 0; fj < 4; ++fj)
                    vreg[fj][i] = xbp[(size_t)(f0 + fj) * T_SZ + t0 + tl + 32 * i];
            } else {
                #pragma unroll
                for (int fj = 0; fj < 4; ++fj) vreg[fj][i] = 0.f;
            }
        }
        if (tid < 32) rz = (t0 >= 1) ? xbp[(size_t)tid * T_SZ + (t0 - 1)] : 0.f;
    };
    auto writeB = [&](int p) {
        #pragma unroll
        for (int i = 0; i < 4; ++i) {
            bf16x4 v;
            v[0] = (bf16)vreg[0][i]; v[1] = (bf16)vreg[1][i];
            v[2] = (bf16)vreg[2][i]; v[3] = (bf16)vreg[3][i];
            *(bf16x4*)&Bs[p][(1 + tl + 32 * i) * LDBL + f0] = v;
        }
        if (tid < 32) Bs[p][tid] = (bf16)rz;
    };
    loadA(0); loadB(0); writeA(0); writeB(0);
    __syncthreads();
    int p = 0;
    for (int ks = 0; ks < 32; ++ks) {
        if (ks + 1 < 32) { loadA(ks + 1); loadB(ks + 1); }
        bf16x8 af[8], blv[2], bhv[2];
        #pragma unroll
        for (int mi = 0; mi < 8; ++mi)
            af[mi] = *(const bf16x8*)&As[p][(mi * 16 + (l & 15)) * LDBL + (l >> 4) * 8];
        #pragma unroll
        for (int ni = 0; ni < 2; ++ni) {
            const int rb = nbase + ni * 16 + (l & 15);
            bhv[ni] = *(const bf16x8*)&Bs[p][rb * LDBL + (l >> 4) * 8];
            blv[ni] = *(const bf16x8*)&Bs[p][(rb + 1) * LDBL + (l >> 4) * 8];
        }
        #pragma unroll
        for (int ni = 0; ni < 2; ++ni)
            #pragma unroll
            for (int mi = 0; mi < 4; ++mi) {
                acc[mi][ni] = __builtin_amdgcn_mfma_f32_16x16x32_bf16(af[mi], blv[ni], acc[mi][ni], 0, 0, 0);
                acc[mi + 4][ni] = __builtin_amdgcn_mfma_f32_16x16x32_bf16(af[mi + 4], bhv[ni], acc[mi + 4][ni], 0, 0, 0);
            }
        if (ks + 1 < 32) { writeA(p ^ 1); writeB(p ^ 1); }
        __syncthreads();
        p ^= 1;
    }
    const float inv = 1.0f / 1024.0f;
    float* ob = out + (size_t)b * OUT_LEN;
    const float* acb = acv + (size_t)b * T_SZ;
    #pragma unroll
    for (int ni = 0; ni < 2; ++ni) {
        const int tt = t0 + nbase + ni * 16 + (l & 15);
        if (tt <= T_SZ) {
            float acs = 0.f;
            if (tt < T_SZ) acs += acb[tt];
            if (tt >= 1)   acs += acb[tt - 1];
            #pragma unroll
            for (int mi = 0; mi < 4; ++mi) {
                const int jl = j0 + mi * 16 + (l >> 4) * 4;
                f32x4 v;
                #pragma unroll
                for (int rr = 0; rr < 4; ++rr)
                    v[rr] = (acc[mi][ni][rr] + acc[mi + 4][ni][rr] + acs) * inv;
                __builtin_nontemporal_store(v, (f32x4*)&ob[(size_t)tt * HOP + jl]);
            }
        }
    }
}

extern "C" void kernel_launch(void* const* d_in, const int* in_sizes, int n_in,
                              void* d_out, int out_size, void* d_ws, size_t ws_size,
                              hipStream_t stream) {
    const float* magn  = (const float*)d_in[0];
    const float* phase = (const float*)d_in[1];
    const float* ac    = (const float*)d_in[2];
    const float* rk    = (const float*)d_in[3];
    const float* ik    = (const float*)d_in[4];
    float* out = (float*)d_out;

    if (ws_size >= WS_NEED) {
        bf16* Xw = (bf16*)d_ws;
        bf16* Wt = Xw + XW_ELEMS;
        cvt_w<<<1024, 256, 0, stream>>>(rk, ik, Wt, Xw);
        cvt_x<<<8192, 256, 0, stream>>>(magn, phase, Xw);
        istft_gemm4<<<2048, 256, 0, stream>>>(Xw, Wt, ac, out);
        istft_tail<<<16, 256, 0, stream>>>(Xw, Wt, ac, out);
    } else {
        istft_fused_legacy<<<528 * 8, 256, 0, stream>>>(magn, phase, ac, rk, ik, out);
    }
}